// Round 3
// baseline (15390.387 us; speedup 1.0000x reference)
//
#include <hip/hip_runtime.h>

// ---------------------------------------------------------------------------
// 2-layer LSTM LM, persistent weights-stationary design for MI355X (gfx950).
//   B=32, S=512, E=H=1024, V=32000.
//   k_emb : gather embedding rows -> bf16 [S][B][1024]
//   k_lstm: 256 persistent WGs (1/CU). Each WG owns 4 h-columns of BOTH
//           layers; all 4 weight column-slices live in LDS as bf16 (128 KB).
//           513 iterations; layer 1 pipelined one step behind layer 0.
//           Custom epoch grid barrier (device-scope atomics) per iteration.
//   k_fc  : logits = h1_final @ Wfc + bfc  (memory-bound on Wfc)
//   k_sm  : row softmax in-place on d_out
// ---------------------------------------------------------------------------

typedef unsigned short ushort_t;
typedef unsigned int uint32;
typedef short short8 __attribute__((ext_vector_type(8)));
typedef float floatx4 __attribute__((ext_vector_type(4)));

#define NWG 256
// workspace layout (bytes)
#define WS_H0 0           // ushort[2][32][1024]  = 131072 B
#define WS_H1 131072      // ushort[2][32][1024]  = 131072 B
#define WS_BAR 262144     // int cnt @+0, int epoch @+128
#define WS_EMBT 262656    // ushort[512][32][1024] = 32 MB
// total ws needed: 262656 + 33554432 = 33,817,088 B

__device__ __forceinline__ ushort_t f2bf(float f) {
  uint32 u = __float_as_uint(f);
  u = (u + 0x7FFFu + ((u >> 16) & 1u)) >> 16;   // RNE, no NaN inputs expected
  return (ushort_t)u;
}
__device__ __forceinline__ float bf2f(ushort_t u) {
  return __uint_as_float(((uint32)u) << 16);
}

// ---------------------------------------------------------------- embedding
// 2048 blocks x 8 rows each (row = t*32+b); 256 thr x float4 = 1024 elems.
__global__ __launch_bounds__(256) void k_emb(const int* __restrict__ x,
                                             const float* __restrict__ emb,
                                             ushort_t* __restrict__ embT) {
  int base = blockIdx.x * 8;
  #pragma unroll
  for (int rr = 0; rr < 8; ++rr) {
    int rid = base + rr;               // t*32 + b
    int t = rid >> 5, b = rid & 31;
    int tok = x[b * 512 + t];
    const float4* src = (const float4*)(emb + (size_t)tok * 1024);
    ushort4* dst = (ushort4*)(embT + (size_t)rid * 1024);
    float4 v = src[threadIdx.x];
    ushort4 o;
    o.x = f2bf(v.x); o.y = f2bf(v.y); o.z = f2bf(v.z); o.w = f2bf(v.w);
    dst[threadIdx.x] = o;
  }
}

// ------------------------------------------------------------- LSTM (persistent)
// LDS weights: [4 mats][16 cols][1024 k] bf16, col-major per col.
//   byte(m,c,k) = m*32768 + c*2048 + ((2k) ^ ((c&7)<<4))
// XOR swizzle applied IDENTICALLY on write and read (R2 fix: read previously
// added 2k after xoring the base -> wrong weights whenever (2k & swz) != 0).
__global__ __launch_bounds__(256, 1) void k_lstm(
    const ushort_t* __restrict__ embT,
    const float* __restrict__ Wx0, const float* __restrict__ Wh0,
    const float* __restrict__ b0,
    const float* __restrict__ Wx1, const float* __restrict__ Wh1,
    const float* __restrict__ b1,
    ushort_t* __restrict__ h0buf, ushort_t* __restrict__ h1buf,
    int* __restrict__ bar_cnt, int* __restrict__ bar_epoch) {

  __shared__ __align__(16) char smem[131072 + 8192 + 1024 + 16];
  float* zbuf = (float*)(smem + 131072);          // [L][kh][mt][16][16] f32
  float* cls  = (float*)(smem + 131072 + 8192);   // c state [2][32][4] f32
  int* okflag = (int*)(smem + 131072 + 8192 + 1024);

  const int tid = threadIdx.x;
  const int wg = blockIdx.x;

  // ---- stage weight column-slices into LDS (one-time, strided reads) ----
  {
    const float* Wsrc[4] = {Wx0, Wh0, Wx1, Wh1};
    int c = tid & 15;                 // local col: c = gate*4 + j
    int klo = (tid >> 4);             // 0..15
    int g = c >> 2, j = c & 3;
    int n = (g << 10) + (wg << 2) + j;    // source column in [1024][4096]
    for (int m = 0; m < 4; ++m) {
      const float* W = Wsrc[m];
      #pragma unroll 4
      for (int khi = 0; khi < 64; ++khi) {
        int k = khi * 16 + klo;
        float v = W[(size_t)k * 4096 + n];
        int off = m * 32768 + c * 2048 + ((k * 2) ^ ((c & 7) << 4));
        *(ushort_t*)(smem + off) = f2bf(v);
      }
    }
  }
  cls[tid] = 0.f;                     // zero c0,c1 (256 floats)
  __syncthreads();

  const int wave = tid >> 6;
  const int lane = tid & 63;
  const int colsel = lane & 15;
  const int kgrp = lane >> 4;          // 0..3
  const int layer = wave >> 1;         // waves 0,1 -> L0 ; 2,3 -> L1 (step t-1)
  const int kh = wave & 1;             // K-half per wave
  const int swz = (colsel & 7) << 4;
  const int mA = layer * 2;            // 0:Wx0 2:Wx1
  const int mB = mA + 1;               // 1:Wh0 3:Wh1
  const char* bAp = smem + mA * 32768 + colsel * 2048;   // unswizzled base
  const char* bBp = smem + mB * 32768 + colsel * 2048;

  for (int t = 0; t <= 512; ++t) {
    const int rp = (t + 1) & 1;        // parity holding h(t-1)
    const int wp = t & 1;              // parity we write this iter
    floatx4 acc0 = {0.f, 0.f, 0.f, 0.f}, acc1 = acc0, acc2 = acc0, acc3 = acc0;
    const bool active = (layer == 0) ? (t < 512) : (t >= 1);
    if (active) {
      const ushort_t* Aa = (layer == 0) ? (embT + (size_t)t * 32768)
                                        : (h0buf + rp * 32768);
      const ushort_t* Ab = (layer == 0) ? (h0buf + rp * 32768)
                                        : (h1buf + rp * 32768);
      const int ke = kh * 512 + kgrp * 8;
      const int row0 = colsel, row1 = colsel + 16;
      // 4 independent MFMA chains (dep distance 4) for 1-wave/SIMD latency hiding
      #pragma unroll 8
      for (int kb = 0; kb < 16; ++kb) {
        int k = ke + kb * 32;
        short8 aA0 = *(const short8*)(Aa + row0 * 1024 + k);
        short8 aA1 = *(const short8*)(Aa + row1 * 1024 + k);
        short8 aB0 = *(const short8*)(Ab + row0 * 1024 + k);
        short8 aB1 = *(const short8*)(Ab + row1 * 1024 + k);
        int kx = (2 * k) ^ swz;        // swizzled byte offset along k
        short8 bA = *(const short8*)(bAp + kx);
        short8 bB = *(const short8*)(bBp + kx);
        acc0 = __builtin_amdgcn_mfma_f32_16x16x32_bf16(aA0, bA, acc0, 0, 0, 0);
        acc1 = __builtin_amdgcn_mfma_f32_16x16x32_bf16(aA1, bA, acc1, 0, 0, 0);
        acc2 = __builtin_amdgcn_mfma_f32_16x16x32_bf16(aB0, bB, acc2, 0, 0, 0);
        acc3 = __builtin_amdgcn_mfma_f32_16x16x32_bf16(aB1, bB, acc3, 0, 0, 0);
      }
    }
    // partial z tiles -> LDS   (C/D layout: col=lane&15, row=(lane>>4)*4+i)
    {
      float* zb = zbuf + ((layer * 2 + kh) * 2) * 256;
      int rbase = kgrp * 4;
      #pragma unroll
      for (int i = 0; i < 4; ++i) {
        zb[(rbase + i) * 16 + colsel] = acc0[i] + acc2[i];
        zb[256 + (rbase + i) * 16 + colsel] = acc1[i] + acc3[i];
      }
    }
    __syncthreads();
    // ---- gate phase: 128 threads per layer -> (row, j) ----
    {
      int L = tid >> 7;
      int r = (tid >> 2) & 31;
      int j = tid & 3;
      bool go = (L == 0) ? (t < 512) : (t >= 1);
      if (go) {
        int hcol = (wg << 2) + j;
        const float* bias = (L == 0) ? b0 : b1;
        int mt = r >> 4, ri = r & 15;
        float z[4];
        #pragma unroll
        for (int g = 0; g < 4; ++g) {
          int cidx = g * 4 + j;
          z[g] = zbuf[(((L * 2 + 0) * 2 + mt) * 16 + ri) * 16 + cidx] +
                 zbuf[(((L * 2 + 1) * 2 + mt) * 16 + ri) * 16 + cidx] +
                 bias[(g << 10) + hcol];
        }
        float c_prev = cls[(L * 32 + r) * 4 + j];
        float ig = 1.f / (1.f + expf(-z[0]));
        float fg = 1.f / (1.f + expf(-z[1]));
        float gg = tanhf(z[2]);
        float og = 1.f / (1.f + expf(-z[3]));
        float cn = fg * c_prev + ig * gg;
        float hn = og * tanhf(cn);
        cls[(L * 32 + r) * 4 + j] = cn;
        ushort_t* hb = (L == 0) ? h0buf : h1buf;
        hb[wp * 32768 + r * 1024 + hcol] = f2bf(hn);
      }
    }
    if (t < 512) {
      // ---- grid barrier (epoch = t+1), bail-out on residency failure ----
      __syncthreads();
      if (tid == 0) {
        __threadfence();
        int prev = __hip_atomic_fetch_add(bar_cnt, 1, __ATOMIC_ACQ_REL,
                                          __HIP_MEMORY_SCOPE_AGENT);
        int ok = 1;
        if (prev == NWG - 1) {
          __hip_atomic_store(bar_cnt, 0, __ATOMIC_RELAXED,
                             __HIP_MEMORY_SCOPE_AGENT);
          __hip_atomic_store(bar_epoch, t + 1, __ATOMIC_RELEASE,
                             __HIP_MEMORY_SCOPE_AGENT);
        } else {
          int spins = 0;
          while (__hip_atomic_load(bar_epoch, __ATOMIC_ACQUIRE,
                                   __HIP_MEMORY_SCOPE_AGENT) < t + 1) {
            __builtin_amdgcn_s_sleep(1);
            if (++spins > (1 << 18)) { ok = 0; break; }
          }
        }
        *okflag = ok;
      }
      __syncthreads();
      if (*okflag == 0) return;        // clean FAIL instead of device wedge
    }
  }
}

// ------------------------------------------------------------------ final FC
// 250 WGs x 256 thr; WG covers 128 vocab cols; h1 staged f32-transposed in LDS.
__global__ __launch_bounds__(256) void k_fc(const ushort_t* __restrict__ h1,
                                            const float* __restrict__ Wfc,
                                            const float* __restrict__ bfc,
                                            float* __restrict__ out) {
  __shared__ float hT[1024 * 32];      // hT[k*32 + r] f32, 128 KB
  int tid = threadIdx.x;
  for (int idx = tid; idx < 32768; idx += 256) {
    int r = idx & 31, k = idx >> 5;
    hT[k * 32 + r] = bf2f(h1[r * 1024 + k]);
  }
  __syncthreads();
  int c = blockIdx.x * 128 + (tid & 127);
  int half = tid >> 7;                 // rows [half*16, half*16+16)
  float acc[16];
  #pragma unroll
  for (int i = 0; i < 16; ++i) acc[i] = 0.f;
  #pragma unroll 8
  for (int k = 0; k < 1024; ++k) {
    float w = Wfc[(size_t)k * 32000 + c];
    const float4* hp = (const float4*)(hT + k * 32 + half * 16);
    float4 h0 = hp[0], h1v = hp[1], h2 = hp[2], h3 = hp[3];
    acc[0] += h0.x * w;  acc[1] += h0.y * w;
    acc[2] += h0.z * w;  acc[3] += h0.w * w;
    acc[4] += h1v.x * w; acc[5] += h1v.y * w;
    acc[6] += h1v.z * w; acc[7] += h1v.w * w;
    acc[8] += h2.x * w;  acc[9] += h2.y * w;
    acc[10] += h2.z * w; acc[11] += h2.w * w;
    acc[12] += h3.x * w; acc[13] += h3.y * w;
    acc[14] += h3.z * w; acc[15] += h3.w * w;
  }
  float bb = bfc[c];
  #pragma unroll
  for (int i = 0; i < 16; ++i)
    out[(size_t)(half * 16 + i) * 32000 + c] = acc[i] + bb;
}

// ------------------------------------------------------------------ softmax
__global__ __launch_bounds__(256) void k_sm(float* __restrict__ out) {
  __shared__ float red[8];
  int r = blockIdx.x, tid = threadIdx.x;
  float* p = out + (size_t)r * 32000;
  float m = -3.4e38f;
  for (int i = tid; i < 32000; i += 256) m = fmaxf(m, p[i]);
  for (int off = 32; off; off >>= 1) m = fmaxf(m, __shfl_down(m, off));
  if ((tid & 63) == 0) red[tid >> 6] = m;
  __syncthreads();
  if (tid == 0) red[4] = fmaxf(fmaxf(red[0], red[1]), fmaxf(red[2], red[3]));
  __syncthreads();
  float M = red[4];
  float s = 0.f;
  for (int i = tid; i < 32000; i += 256) {
    float e = expf(p[i] - M);
    p[i] = e;
    s += e;
  }
  for (int off = 32; off; off >>= 1) s += __shfl_down(s, off);
  if ((tid & 63) == 0) red[tid >> 6] = s;
  __syncthreads();
  if (tid == 0) red[5] = red[0] + red[1] + red[2] + red[3];
  __syncthreads();
  float inv = 1.f / red[5];
  for (int i = tid; i < 32000; i += 256) p[i] *= inv;
}

// ---------------------------------------------------------------------------
extern "C" void kernel_launch(void* const* d_in, const int* in_sizes, int n_in,
                              void* d_out, int out_size, void* d_ws,
                              size_t ws_size, hipStream_t stream) {
  const int* x = (const int*)d_in[0];
  const float* emb = (const float*)d_in[1];
  const float* Wx0 = (const float*)d_in[2];
  const float* Wh0 = (const float*)d_in[3];
  const float* b0 = (const float*)d_in[4];
  const float* Wx1 = (const float*)d_in[5];
  const float* Wh1 = (const float*)d_in[6];
  const float* b1 = (const float*)d_in[7];
  const float* Wfc = (const float*)d_in[8];
  const float* bfc = (const float*)d_in[9];

  char* ws = (char*)d_ws;
  ushort_t* h0buf = (ushort_t*)(ws + WS_H0);
  ushort_t* h1buf = (ushort_t*)(ws + WS_H1);
  int* bar_cnt = (int*)(ws + WS_BAR);
  int* bar_epoch = (int*)(ws + WS_BAR + 128);
  ushort_t* embT = (ushort_t*)(ws + WS_EMBT);

  // zero h state (h(-1)=0) and barrier counters every call (ws is re-poisoned)
  hipMemsetAsync(ws, 0, WS_EMBT, stream);

  k_emb<<<dim3(2048), dim3(256), 0, stream>>>(x, emb, embT);
  k_lstm<<<dim3(NWG), dim3(256), 0, stream>>>(embT, Wx0, Wh0, b0, Wx1, Wh1, b1,
                                              h0buf, h1buf, bar_cnt, bar_epoch);
  // final h1(511) written at iteration t=512 -> parity 0
  k_fc<<<dim3(250), dim3(256), 0, stream>>>(h1buf, Wfc, bfc, (float*)d_out);
  k_sm<<<dim3(32), dim3(256), 0, stream>>>((float*)d_out);
}

// Round 4
// 9566.856 us; speedup vs baseline: 1.6087x; 1.6087x over previous
//
#include <hip/hip_runtime.h>

// ---------------------------------------------------------------------------
// 2-layer LSTM LM, persistent weights-stationary design for MI355X (gfx950).
//   B=32, S=512, E=H=1024, V=32000.
//   k_emb : gather embedding rows -> bf16 [S][B][1024]
//   k_lstm: 256 persistent WGs (1/CU). Weight column-slices in LDS (128 KB).
//           Layer 1 pipelined one step behind layer 0.
//           R4: fence-free step sync. h0/h1 move via AGENT-scope relaxed
//           atomics (bypass non-coherent per-XCD L2 -> coherent point), so
//           no wbl2/inv storms; barrier is a contention-free flag array
//           polled with relaxed atomic loads. (R3: acquire-per-poll caused
//           L2-invalidate storms -> 29.7us/step, MfmaUtil 1.4%.)
//   k_fc  : logits = h1_final @ Wfc + bfc  (memory-bound on Wfc)
//   k_sm  : row softmax in-place on d_out
// ---------------------------------------------------------------------------

typedef unsigned short ushort_t;
typedef unsigned int uint32;
typedef unsigned long long uint64;
typedef short short8 __attribute__((ext_vector_type(8)));
typedef float floatx4 __attribute__((ext_vector_type(4)));

#define NWG 256
// workspace layout (bytes)
#define WS_H0 0           // ushort[2][32][1024]  = 131072 B (slot = idx&1)
#define WS_H1 131072      // ushort[2][32][1024]  = 131072 B
#define WS_FLAGS 262144   // int[256] = 1024 B
#define WS_EMBT 263168    // ushort[512][32][1024] = 32 MB
// total ws needed: 263168 + 33554432 = 33,817,600 B

__device__ __forceinline__ ushort_t f2bf(float f) {
  uint32 u = __float_as_uint(f);
  u = (u + 0x7FFFu + ((u >> 16) & 1u)) >> 16;   // RNE, no NaN inputs expected
  return (ushort_t)u;
}
__device__ __forceinline__ float bf2f(ushort_t u) {
  return __uint_as_float(((uint32)u) << 16);
}

// 16B fragment via two AGENT-scope relaxed atomic b64 loads (bypass L1/L2,
// read the device coherence point -- always fresh, no fence needed).
__device__ __forceinline__ short8 ld_h16(const ushort_t* p) {
  union { uint64 u[2]; short8 s; } v;
  v.u[0] = __hip_atomic_load((const uint64*)p, __ATOMIC_RELAXED,
                             __HIP_MEMORY_SCOPE_AGENT);
  v.u[1] = __hip_atomic_load((const uint64*)(p + 4), __ATOMIC_RELAXED,
                             __HIP_MEMORY_SCOPE_AGENT);
  return v.s;
}

// ---------------------------------------------------------------- embedding
// 2048 blocks x 8 rows each (row = t*32+b); 256 thr x float4 = 1024 elems.
__global__ __launch_bounds__(256) void k_emb(const int* __restrict__ x,
                                             const float* __restrict__ emb,
                                             ushort_t* __restrict__ embT) {
  int base = blockIdx.x * 8;
  #pragma unroll
  for (int rr = 0; rr < 8; ++rr) {
    int rid = base + rr;               // t*32 + b
    int t = rid >> 5, b = rid & 31;
    int tok = x[b * 512 + t];
    const float4* src = (const float4*)(emb + (size_t)tok * 1024);
    ushort4* dst = (ushort4*)(embT + (size_t)rid * 1024);
    float4 v = src[threadIdx.x];
    ushort4 o;
    o.x = f2bf(v.x); o.y = f2bf(v.y); o.z = f2bf(v.z); o.w = f2bf(v.w);
    dst[threadIdx.x] = o;
  }
}

// ------------------------------------------------------------- LSTM (persistent)
// LDS weights: [4 mats][16 cols][1024 k] bf16, col-major per col.
//   byte(m,c,k) = m*32768 + c*2048 + ((2k) ^ ((c&7)<<4))   (write == read)
// Slot numbering: h(s) lives in slot s+1; slot 0 = zeros. Ring addr = slot&1.
//   iter t: read h0 slot t, h1 slot t-1; write h0 slot t+1, h1 slot t.
__global__ __launch_bounds__(256, 1) void k_lstm(
    const ushort_t* __restrict__ embT,
    const float* __restrict__ Wx0, const float* __restrict__ Wh0,
    const float* __restrict__ b0,
    const float* __restrict__ Wx1, const float* __restrict__ Wh1,
    const float* __restrict__ b1,
    ushort_t* __restrict__ h0buf, ushort_t* __restrict__ h1buf,
    int* __restrict__ flags) {

  // LDS: 128K weights | zbuf [8 tiles][16][18] f32 = 9216 B | c 1KB | ok 16B
  __shared__ __align__(16) char smem[131072 + 9216 + 1024 + 16];
  float* zbuf = (float*)(smem + 131072);
  float* cls  = (float*)(smem + 131072 + 9216);   // c state [2][32][4] f32
  int* okflag = (int*)(smem + 131072 + 9216 + 1024);

  const int tid = threadIdx.x;
  const int wg = blockIdx.x;

  // ---- stage weight column-slices into LDS (one-time, strided reads) ----
  {
    const float* Wsrc[4] = {Wx0, Wh0, Wx1, Wh1};
    int c = tid & 15;                 // local col: c = gate*4 + j
    int klo = (tid >> 4);             // 0..15
    int g = c >> 2, j = c & 3;
    int n = (g << 10) + (wg << 2) + j;    // source column in [1024][4096]
    for (int m = 0; m < 4; ++m) {
      const float* W = Wsrc[m];
      #pragma unroll 4
      for (int khi = 0; khi < 64; ++khi) {
        int k = khi * 16 + klo;
        float v = W[(size_t)k * 4096 + n];
        int off = m * 32768 + c * 2048 + ((k * 2) ^ ((c & 7) << 4));
        *(ushort_t*)(smem + off) = f2bf(v);
      }
    }
  }
  cls[tid] = 0.f;                     // zero c0,c1 (256 floats)
  __syncthreads();

  const int wave = tid >> 6;
  const int lane = tid & 63;
  const int colsel = lane & 15;
  const int kgrp = lane >> 4;          // 0..3
  const int layer = wave >> 1;         // waves 0,1 -> L0 ; 2,3 -> L1 (step t-1)
  const int kh = wave & 1;             // K-half per wave
  const int swz = (colsel & 15) ? ((colsel & 7) << 4) : 0; // == (colsel&7)<<4
  const int mA = layer * 2;            // 0:Wx0 2:Wx1
  const int mB = mA + 1;               // 1:Wh0 3:Wh1
  const char* bAp = smem + mA * 32768 + colsel * 2048;   // unswizzled base
  const char* bBp = smem + mB * 32768 + colsel * 2048;

  // gate-phase per-thread constants (hoisted out of the loop)
  const int gL = tid >> 7;
  const int gr = (tid >> 2) & 31;
  const int gj = tid & 3;
  const int ghcol = (wg << 2) + gj;
  float gbias[4];
  {
    const float* bias = (gL == 0) ? b0 : b1;
    #pragma unroll
    for (int g = 0; g < 4; ++g) gbias[g] = bias[(g << 10) + ghcol];
  }
  ushort_t* const ghb = (gL == 0) ? h0buf : h1buf;

  for (int t = 0; t <= 512; ++t) {
    floatx4 acc0 = {0.f, 0.f, 0.f, 0.f}, acc1 = acc0, acc2 = acc0, acc3 = acc0;
    const bool active = (layer == 0) ? (t < 512) : (t >= 1);
    if (active) {
      // L0: Aa = embT(t) [cached], Ab = h0 slot t [atomic]
      // L1: Aa = h0 slot t [atomic], Ab = h1 slot t-1 [atomic]
      const ushort_t* Aa = (layer == 0) ? (embT + (size_t)t * 32768)
                                        : (h0buf + (t & 1) * 32768);
      const ushort_t* Ab = (layer == 0) ? (h0buf + (t & 1) * 32768)
                                        : (h1buf + ((t - 1) & 1) * 32768);
      const int ke = kh * 512 + kgrp * 8;
      const int row0 = colsel, row1 = colsel + 16;
      // 4 independent MFMA chains (dep distance 4) for 1-wave/SIMD latency hiding
      #pragma unroll 8
      for (int kb = 0; kb < 16; ++kb) {
        int k = ke + kb * 32;
        short8 aA0, aA1;
        if (layer == 0) {
          aA0 = *(const short8*)(Aa + row0 * 1024 + k);
          aA1 = *(const short8*)(Aa + row1 * 1024 + k);
        } else {
          aA0 = ld_h16(Aa + row0 * 1024 + k);
          aA1 = ld_h16(Aa + row1 * 1024 + k);
        }
        short8 aB0 = ld_h16(Ab + row0 * 1024 + k);
        short8 aB1 = ld_h16(Ab + row1 * 1024 + k);
        int kx = (2 * k) ^ swz;        // swizzled byte offset along k
        short8 bA = *(const short8*)(bAp + kx);
        short8 bB = *(const short8*)(bBp + kx);
        acc0 = __builtin_amdgcn_mfma_f32_16x16x32_bf16(aA0, bA, acc0, 0, 0, 0);
        acc1 = __builtin_amdgcn_mfma_f32_16x16x32_bf16(aA1, bA, acc1, 0, 0, 0);
        acc2 = __builtin_amdgcn_mfma_f32_16x16x32_bf16(aB0, bB, acc2, 0, 0, 0);
        acc3 = __builtin_amdgcn_mfma_f32_16x16x32_bf16(aB1, bB, acc3, 0, 0, 0);
      }
    }
    // partial z tiles -> LDS  (C/D layout: col=lane&15, row=(lane>>4)*4+i)
    // zbuf tile T = (layer*2+kh)*2 + tile, elem = ri*18 + c  (pad 16->18:
    // gate-phase reads were 8-way bank conflicts at stride 16)
    {
      float* zb = zbuf + ((layer * 2 + kh) * 2) * 288;
      int rbase = kgrp * 4;
      #pragma unroll
      for (int i = 0; i < 4; ++i) {
        zb[(rbase + i) * 18 + colsel] = acc0[i] + acc2[i];
        zb[288 + (rbase + i) * 18 + colsel] = acc1[i] + acc3[i];
      }
    }
    __syncthreads();
    // ---- gate phase: 128 threads per layer -> (row, j) ----
    {
      bool go = (gL == 0) ? (t < 512) : (t >= 1);
      if (go) {
        int mt = gr >> 4, ri = gr & 15;
        float z[4];
        #pragma unroll
        for (int g = 0; g < 4; ++g) {
          int cidx = g * 4 + gj;
          z[g] = zbuf[((gL * 2 + 0) * 2 + mt) * 288 + ri * 18 + cidx] +
                 zbuf[((gL * 2 + 1) * 2 + mt) * 288 + ri * 18 + cidx] +
                 gbias[g];
        }
        float c_prev = cls[(gL * 32 + gr) * 4 + gj];
        float ig = 1.f / (1.f + expf(-z[0]));
        float fg = 1.f / (1.f + expf(-z[1]));
        float gg = tanhf(z[2]);
        float og = 1.f / (1.f + expf(-z[3]));
        float cn = fg * c_prev + ig * gg;
        float hn = og * tanhf(cn);
        cls[(gL * 32 + gr) * 4 + gj] = cn;
        // write slot: L0 -> t+1, L1 -> t ; pack 2 cols -> one b32 atomic store
        int wslot = (gL == 0) ? (t + 1) : t;
        ushort_t hs = f2bf(hn);
        uint32 up = (uint32)(unsigned short)__shfl_xor((int)hs, 1);
        if ((gj & 1) == 0) {
          uint32 packed = (uint32)hs | (up << 16);
          uint32* dst = (uint32*)(ghb + (wslot & 1) * 32768 + gr * 1024 +
                                  (ghcol & ~1));
          __hip_atomic_store(dst, packed, __ATOMIC_RELAXED,
                             __HIP_MEMORY_SCOPE_AGENT);
        }
      }
    }
    if (t < 512) {
      // ---- flag-array barrier: no fences, no RMW contention ----
      __syncthreads();                 // drains vmcnt -> h stores are visible
      if (tid == 0) {
        asm volatile("s_waitcnt vmcnt(0)" ::: "memory");
        __hip_atomic_store(&flags[wg], t + 1, __ATOMIC_RELAXED,
                           __HIP_MEMORY_SCOPE_AGENT);
      }
      if (wave == 0) {                 // 64 lanes x 4 flags each
        int ok = 1, spins = 0;
        for (;;) {
          int done = 1;
          #pragma unroll
          for (int q = 0; q < 4; ++q) {
            int v = __hip_atomic_load(&flags[lane * 4 + q], __ATOMIC_RELAXED,
                                      __HIP_MEMORY_SCOPE_AGENT);
            if (v < t + 1) done = 0;
          }
          if (__all(done)) break;
          __builtin_amdgcn_s_sleep(2);
          if (++spins > (1 << 16)) { ok = 0; break; }
        }
        if (lane == 0) *okflag = ok;
      }
      __syncthreads();
      if (*okflag == 0) return;        // clean FAIL instead of device wedge
    }
  }
}

// ------------------------------------------------------------------ final FC
// 250 WGs x 256 thr; WG covers 128 vocab cols; h1 staged f32-transposed in LDS.
// h1(511) = slot 512 -> ring parity 0.
__global__ __launch_bounds__(256) void k_fc(const ushort_t* __restrict__ h1,
                                            const float* __restrict__ Wfc,
                                            const float* __restrict__ bfc,
                                            float* __restrict__ out) {
  __shared__ float hT[1024 * 32];      // hT[k*32 + r] f32, 128 KB
  int tid = threadIdx.x;
  for (int idx = tid; idx < 32768; idx += 256) {
    int r = idx & 31, k = idx >> 5;
    hT[k * 32 + r] = bf2f(h1[r * 1024 + k]);
  }
  __syncthreads();
  int c = blockIdx.x * 128 + (tid & 127);
  int half = tid >> 7;                 // rows [half*16, half*16+16)
  float acc[16];
  #pragma unroll
  for (int i = 0; i < 16; ++i) acc[i] = 0.f;
  #pragma unroll 8
  for (int k = 0; k < 1024; ++k) {
    float w = Wfc[(size_t)k * 32000 + c];
    const float4* hp = (const float4*)(hT + k * 32 + half * 16);
    float4 h0 = hp[0], h1v = hp[1], h2 = hp[2], h3 = hp[3];
    acc[0] += h0.x * w;  acc[1] += h0.y * w;
    acc[2] += h0.z * w;  acc[3] += h0.w * w;
    acc[4] += h1v.x * w; acc[5] += h1v.y * w;
    acc[6] += h1v.z * w; acc[7] += h1v.w * w;
    acc[8] += h2.x * w;  acc[9] += h2.y * w;
    acc[10] += h2.z * w; acc[11] += h2.w * w;
    acc[12] += h3.x * w; acc[13] += h3.y * w;
    acc[14] += h3.z * w; acc[15] += h3.w * w;
  }
  float bb = bfc[c];
  #pragma unroll
  for (int i = 0; i < 16; ++i)
    out[(size_t)(half * 16 + i) * 32000 + c] = acc[i] + bb;
}

// ------------------------------------------------------------------ softmax
__global__ __launch_bounds__(256) void k_sm(float* __restrict__ out) {
  __shared__ float red[8];
  int r = blockIdx.x, tid = threadIdx.x;
  float* p = out + (size_t)r * 32000;
  float m = -3.4e38f;
  for (int i = tid; i < 32000; i += 256) m = fmaxf(m, p[i]);
  for (int off = 32; off; off >>= 1) m = fmaxf(m, __shfl_down(m, off));
  if ((tid & 63) == 0) red[tid >> 6] = m;
  __syncthreads();
  if (tid == 0) red[4] = fmaxf(fmaxf(red[0], red[1]), fmaxf(red[2], red[3]));
  __syncthreads();
  float M = red[4];
  float s = 0.f;
  for (int i = tid; i < 32000; i += 256) {
    float e = expf(p[i] - M);
    p[i] = e;
    s += e;
  }
  for (int off = 32; off; off >>= 1) s += __shfl_down(s, off);
  if ((tid & 63) == 0) red[tid >> 6] = s;
  __syncthreads();
  if (tid == 0) red[5] = red[0] + red[1] + red[2] + red[3];
  __syncthreads();
  float inv = 1.f / red[5];
  for (int i = tid; i < 32000; i += 256) p[i] *= inv;
}

// ---------------------------------------------------------------------------
extern "C" void kernel_launch(void* const* d_in, const int* in_sizes, int n_in,
                              void* d_out, int out_size, void* d_ws,
                              size_t ws_size, hipStream_t stream) {
  const int* x = (const int*)d_in[0];
  const float* emb = (const float*)d_in[1];
  const float* Wx0 = (const float*)d_in[2];
  const float* Wh0 = (const float*)d_in[3];
  const float* b0 = (const float*)d_in[4];
  const float* Wx1 = (const float*)d_in[5];
  const float* Wh1 = (const float*)d_in[6];
  const float* b1 = (const float*)d_in[7];
  const float* Wfc = (const float*)d_in[8];
  const float* bfc = (const float*)d_in[9];

  char* ws = (char*)d_ws;
  ushort_t* h0buf = (ushort_t*)(ws + WS_H0);
  ushort_t* h1buf = (ushort_t*)(ws + WS_H1);
  int* flags = (int*)(ws + WS_FLAGS);
  ushort_t* embT = (ushort_t*)(ws + WS_EMBT);

  // zero h rings + flags every call (ws is re-poisoned 0xAA by harness)
  hipMemsetAsync(ws, 0, WS_EMBT, stream);

  k_emb<<<dim3(2048), dim3(256), 0, stream>>>(x, emb, embT);
  k_lstm<<<dim3(NWG), dim3(256), 0, stream>>>(embT, Wx0, Wh0, b0, Wx1, Wh1, b1,
                                              h0buf, h1buf, flags);
  // final h1(511) = slot 512 -> ring parity 0
  k_fc<<<dim3(250), dim3(256), 0, stream>>>(h1buf, Wfc, bfc, (float*)d_out);
  k_sm<<<dim3(32), dim3(256), 0, stream>>>((float*)d_out);
}